// Round 9
// baseline (641.429 us; speedup 1.0000x reference)
//
#include <hip/hip_runtime.h>

// BottleneckA fully fused. R9: occupancy-first redesign from R7/R8 counters
// (everything idle, ~1.5 blocks/CU). W is NEVER staged in LDS: MFMA W-fragments
// are loaded straight global->register (pattern is 16 rows x 64B contiguous =
// perfectly coalesced L2 reads; W=1.18MB is L2-resident). Stages B/C have NO
// barriers. Stage A: Xsm double-buffered (2x4KB), one lds-only barrier/iter.
// LDS = 32KB Hsm + 8KB Xsm = 40KB -> 4 blocks/CU (exactly 160KB).
// Mappings/swizzle/epilogues identical to the R7-verified kernel.

#define NPIX 3136
#define BATCH 16

typedef __attribute__((ext_vector_type(8))) short short8;
typedef __attribute__((ext_vector_type(4))) float v4f;

__device__ __forceinline__ unsigned short f2bf(float f) {
    union { float f; unsigned u; } v; v.f = f;
    unsigned r = v.u + 0x7fffu + ((v.u >> 16) & 1u);
    return (unsigned short)(r >> 16);
}

__device__ __forceinline__ short8 ldg8(const unsigned short* p) {
    return *reinterpret_cast<const short8*>(p);   // global_load_dwordx4
}

__device__ __forceinline__ void bar_lds_only() {
    asm volatile("s_waitcnt lgkmcnt(0)" ::: "memory");
    __builtin_amdgcn_s_barrier();
    __builtin_amdgcn_sched_barrier(0);
}

// ---- W f32 -> bf16 (concatenated W1|W2|W3), 4 elems/thread ----
__global__ void convert_w(const float* __restrict__ W1, const float* __restrict__ W2,
                          const float* __restrict__ W3, unsigned short* __restrict__ Wb) {
    size_t e = ((size_t)blockIdx.x * 256 + threadIdx.x) * 4;
    const float* src; size_t off;
    if (e < 262144)      { src = W1; off = e; }
    else if (e < 327680) { src = W2; off = e - 262144; }
    else                 { src = W3; off = e - 327680; }
    float4 v = *reinterpret_cast<const float4*>(&src[off]);
    uint2 p;
    p.x = (unsigned)f2bf(v.x) | ((unsigned)f2bf(v.y) << 16);
    p.y = (unsigned)f2bf(v.z) | ((unsigned)f2bf(v.w) << 16);
    *reinterpret_cast<uint2*>(&Wb[e]) = p;
}

__global__ __launch_bounds__(256, 4) void moe_block(
    const float* __restrict__ x, const unsigned short* __restrict__ Wb,
    const float* __restrict__ b1, const float* __restrict__ b2,
    const float* __restrict__ b3, const float* __restrict__ gate,
    float* __restrict__ out)
{
    __shared__ __attribute__((aligned(16))) unsigned short Hsm[64 * 256];   // 32KB
    __shared__ __attribute__((aligned(16))) unsigned short Xsm[2][64 * 32]; // 8KB dbuf

    const unsigned short* W1b = Wb;
    const unsigned short* W2b = Wb + 262144;
    const unsigned short* W3b = Wb + 327680;

    const int b    = blockIdx.z;
    const int p0   = blockIdx.x * 64;
    const int t    = threadIdx.x;
    const int lane = t & 63;
    const int wave = t >> 6;
    const int wm   = wave * 64;
    const int l15  = lane & 15;
    const int quad = lane >> 4;

    char* hb = reinterpret_cast<char*>(Hsm);
    v4f acc[4][4];

    // W fragment base pointers (global, register operands)
    const unsigned short* wf1 = W1b + (size_t)(wm + l15) * 1024 + quad * 8;
    const unsigned short* wf2 = W2b + (size_t)(wm + l15) * 256 + quad * 8;
    const unsigned short* wf3 = W3b + (size_t)(wm + l15) * 256 + quad * 8;

    // ---------------- Stage A: h1 = relu(g ∘ (W1·x + b1)) ----------------
    #pragma unroll
    for (int i = 0; i < 4; ++i)
        #pragma unroll
        for (int j = 0; j < 4; ++j) acc[i][j] = (v4f){0.f, 0.f, 0.f, 0.f};

    {
        const int cp   = t & 15;     // channel pair: c = 2cp, 2cp+1
        const int pgrp = t >> 4;     // pixel group: 4 pix each
        const float* xg = x + ((size_t)(b * 1024 + 2 * cp)) * NPIX + p0 + pgrp * 4;

        // prologue: x(0) -> regs -> Xsm[0]; barrier.
        float4 a0 = *reinterpret_cast<const float4*>(xg);
        float4 a1 = *reinterpret_cast<const float4*>(xg + NPIX);
        {
            unsigned* xw = reinterpret_cast<unsigned*>(&Xsm[0][pgrp * 128 + 2 * cp]);
            unsigned u0 = (unsigned)f2bf(a0.x) | ((unsigned)f2bf(a1.x) << 16);
            unsigned u1 = (unsigned)f2bf(a0.y) | ((unsigned)f2bf(a1.y) << 16);
            unsigned u2 = (unsigned)f2bf(a0.z) | ((unsigned)f2bf(a1.z) << 16);
            unsigned u3 = (unsigned)f2bf(a0.w) | ((unsigned)f2bf(a1.w) << 16);
            xw[0] = u0; xw[16] = u1; xw[32] = u2; xw[48] = u3;
        }
        bar_lds_only();

        for (int kt = 0; kt < 32; ++kt) {
            // issue x(kt+1) HBM loads (consumed by ds_write at iter bottom)
            if (kt < 31) {
                const float* xp = xg + (size_t)(kt + 1) * 32 * NPIX;
                a0 = *reinterpret_cast<const float4*>(xp);
                a1 = *reinterpret_cast<const float4*>(xp + NPIX);
            }
            // issue W1 fragment loads for this k-tile (L2; used after cf reads)
            short8 rf[4], cf[4];
            #pragma unroll
            for (int mt = 0; mt < 4; ++mt)
                rf[mt] = ldg8(wf1 + (size_t)mt * 16384 + kt * 32);
            // cf from Xsm[kt&1] (written previous iter, barrier'd)
            #pragma unroll
            for (int nt = 0; nt < 4; ++nt)
                cf[nt] = *reinterpret_cast<const short8*>(
                    &Xsm[kt & 1][(nt * 16 + l15) * 32 + quad * 8]);
            #pragma unroll
            for (int mt = 0; mt < 4; ++mt)
                #pragma unroll
                for (int nt = 0; nt < 4; ++nt)
                    acc[mt][nt] = __builtin_amdgcn_mfma_f32_16x16x32_bf16(
                        rf[mt], cf[nt], acc[mt][nt], 0, 0, 0);
            // write x(kt+1) into the alternate buffer (no reader this interval)
            if (kt < 31) {
                unsigned* xw = reinterpret_cast<unsigned*>(
                    &Xsm[(kt + 1) & 1][pgrp * 128 + 2 * cp]);
                unsigned u0 = (unsigned)f2bf(a0.x) | ((unsigned)f2bf(a1.x) << 16);
                unsigned u1 = (unsigned)f2bf(a0.y) | ((unsigned)f2bf(a1.y) << 16);
                unsigned u2 = (unsigned)f2bf(a0.z) | ((unsigned)f2bf(a1.z) << 16);
                unsigned u3 = (unsigned)f2bf(a0.w) | ((unsigned)f2bf(a1.w) << 16);
                xw[0] = u0; xw[16] = u1; xw[32] = u2; xw[48] = u3;
                bar_lds_only();  // X(kt+1) visible before iter kt+1 reads it
            }
        }
    }

    // epilogue A -> Hsm[pix][o1], swizzled
    #pragma unroll
    for (int mt = 0; mt < 4; ++mt) {
        const int o = wm + mt * 16 + quad * 4;
        const float4 bi = *reinterpret_cast<const float4*>(&b1[o]);
        const float4 gv = *reinterpret_cast<const float4*>(&gate[b * 256 + o]);
        const float g0 = gv.x > 0.f ? gv.x : 0.f;
        const float g1 = gv.y > 0.f ? gv.y : 0.f;
        const float g2 = gv.z > 0.f ? gv.z : 0.f;
        const float g3 = gv.w > 0.f ? gv.w : 0.f;
        #pragma unroll
        for (int nt = 0; nt < 4; ++nt) {
            const int pix = nt * 16 + l15;
            float v0 = (acc[mt][nt][0] + bi.x) * g0;
            float v1 = (acc[mt][nt][1] + bi.y) * g1;
            float v2 = (acc[mt][nt][2] + bi.z) * g2;
            float v3 = (acc[mt][nt][3] + bi.w) * g3;
            v0 = v0 > 0.f ? v0 : 0.f; v1 = v1 > 0.f ? v1 : 0.f;
            v2 = v2 > 0.f ? v2 : 0.f; v3 = v3 > 0.f ? v3 : 0.f;
            uint2 pq;
            pq.x = (unsigned)f2bf(v0) | ((unsigned)f2bf(v1) << 16);
            pq.y = (unsigned)f2bf(v2) | ((unsigned)f2bf(v3) << 16);
            const unsigned off = (unsigned)(pix * 512 + o * 2) ^ (unsigned)((pix & 7) << 4);
            *reinterpret_cast<uint2*>(hb + off) = pq;
        }
    }
    __syncthreads();  // h1 visible to all waves

    // ------- Stage B: h2 = relu(g ∘ (W2·h1 + b2)) — BARRIER-FREE k-loop -----
    #pragma unroll
    for (int i = 0; i < 4; ++i)
        #pragma unroll
        for (int j = 0; j < 4; ++j) acc[i][j] = (v4f){0.f, 0.f, 0.f, 0.f};

    #pragma unroll
    for (int bt = 0; bt < 8; ++bt) {
        short8 rf[4], cf[4];
        #pragma unroll
        for (int mt = 0; mt < 4; ++mt)
            rf[mt] = ldg8(wf2 + (size_t)mt * 4096 + bt * 32);
        #pragma unroll
        for (int nt = 0; nt < 4; ++nt) {
            const int row = nt * 16 + l15;
            const unsigned off =
                (unsigned)(row * 512 + bt * 64 + quad * 16) ^ (unsigned)((row & 7) << 4);
            cf[nt] = *reinterpret_cast<const short8*>(hb + off);
        }
        #pragma unroll
        for (int mt = 0; mt < 4; ++mt)
            #pragma unroll
            for (int nt = 0; nt < 4; ++nt)
                acc[mt][nt] = __builtin_amdgcn_mfma_f32_16x16x32_bf16(
                    rf[mt], cf[nt], acc[mt][nt], 0, 0, 0);
    }
    __syncthreads();  // all h1 reads complete before overwrite

    // epilogue B -> Hsm[pix][o2], swizzled (overwrites h1)
    #pragma unroll
    for (int mt = 0; mt < 4; ++mt) {
        const int o = wm + mt * 16 + quad * 4;
        const float4 bi = *reinterpret_cast<const float4*>(&b2[o]);
        const float4 gv = *reinterpret_cast<const float4*>(&gate[b * 256 + o]);
        const float g0 = gv.x > 0.f ? gv.x : 0.f;
        const float g1 = gv.y > 0.f ? gv.y : 0.f;
        const float g2 = gv.z > 0.f ? gv.z : 0.f;
        const float g3 = gv.w > 0.f ? gv.w : 0.f;
        #pragma unroll
        for (int nt = 0; nt < 4; ++nt) {
            const int pix = nt * 16 + l15;
            float v0 = (acc[mt][nt][0] + bi.x) * g0;
            float v1 = (acc[mt][nt][1] + bi.y) * g1;
            float v2 = (acc[mt][nt][2] + bi.z) * g2;
            float v3 = (acc[mt][nt][3] + bi.w) * g3;
            v0 = v0 > 0.f ? v0 : 0.f; v1 = v1 > 0.f ? v1 : 0.f;
            v2 = v2 > 0.f ? v2 : 0.f; v3 = v3 > 0.f ? v3 : 0.f;
            uint2 pq;
            pq.x = (unsigned)f2bf(v0) | ((unsigned)f2bf(v1) << 16);
            pq.y = (unsigned)f2bf(v2) | ((unsigned)f2bf(v3) << 16);
            const unsigned off = (unsigned)(pix * 512 + o * 2) ^ (unsigned)((pix & 7) << 4);
            *reinterpret_cast<uint2*>(hb + off) = pq;
        }
    }
    __syncthreads();  // h2 visible for stage C

    // ------- Stage C: out = relu(W3·h2 + b3) + x — BARRIER-FREE k-loops -----
    for (int ch = 0; ch < 4; ++ch) {
        const int oc0 = ch * 256;
        #pragma unroll
        for (int i = 0; i < 4; ++i)
            #pragma unroll
            for (int j = 0; j < 4; ++j) acc[i][j] = (v4f){0.f, 0.f, 0.f, 0.f};

        #pragma unroll
        for (int jt = 0; jt < 8; ++jt) {
            const int k0 = jt * 32;
            short8 rf[4], cf[4];
            #pragma unroll
            for (int mt = 0; mt < 4; ++mt) {       // rows = pix from Hsm (h2)
                const int row = mt * 16 + l15;
                const unsigned off =
                    (unsigned)(row * 512 + k0 * 2 + quad * 16) ^ (unsigned)((row & 7) << 4);
                rf[mt] = *reinterpret_cast<const short8*>(hb + off);
            }
            #pragma unroll
            for (int nt = 0; nt < 4; ++nt)         // cols = o3 from W3 (global)
                cf[nt] = ldg8(wf3 + (size_t)(oc0 + nt * 16) * 256 + k0);
            #pragma unroll
            for (int mt = 0; mt < 4; ++mt)
                #pragma unroll
                for (int nt = 0; nt < 4; ++nt)
                    acc[mt][nt] = __builtin_amdgcn_mfma_f32_16x16x32_bf16(
                        rf[mt], cf[nt], acc[mt][nt], 0, 0, 0);
        }

        // chunk epilogue: relu + bias + residual, f32 out [b][o][pix]
        #pragma unroll
        for (int nt = 0; nt < 4; ++nt) {
            const int o = oc0 + wm + nt * 16 + l15;
            const float bi = b3[o];
            #pragma unroll
            for (int mt = 0; mt < 4; ++mt) {
                const int pix = p0 + mt * 16 + quad * 4;
                const size_t base = ((size_t)(b * 1024 + o)) * NPIX + pix;
                const float4 xr = *reinterpret_cast<const float4*>(&x[base]);
                float v0 = acc[mt][nt][0] + bi, v1 = acc[mt][nt][1] + bi;
                float v2 = acc[mt][nt][2] + bi, v3 = acc[mt][nt][3] + bi;
                float4 ov;
                ov.x = (v0 > 0.f ? v0 : 0.f) + xr.x;
                ov.y = (v1 > 0.f ? v1 : 0.f) + xr.y;
                ov.z = (v2 > 0.f ? v2 : 0.f) + xr.z;
                ov.w = (v3 > 0.f ? v3 : 0.f) + xr.w;
                *reinterpret_cast<float4*>(&out[base]) = ov;
            }
        }
    }
}

extern "C" void kernel_launch(void* const* d_in, const int* in_sizes, int n_in,
                              void* d_out, int out_size, void* d_ws, size_t ws_size,
                              hipStream_t stream) {
    const float* x    = (const float*)d_in[0];
    const float* gate = (const float*)d_in[1];
    const float* W1   = (const float*)d_in[2];
    const float* b1   = (const float*)d_in[3];
    const float* W2   = (const float*)d_in[4];
    const float* b2   = (const float*)d_in[5];
    const float* W3   = (const float*)d_in[6];
    const float* b3   = (const float*)d_in[7];
    float* out = (float*)d_out;

    unsigned short* Wb = (unsigned short*)d_ws;   // 589824 ushorts ≈ 1.18 MB

    dim3 blk(256);
    convert_w<<<576, blk, 0, stream>>>(W1, W2, W3, Wb);
    moe_block<<<dim3(49, 1, BATCH), blk, 0, stream>>>(x, Wb, b1, b2, b3, gate, out);
}